// Round 6
// baseline (204.055 us; speedup 1.0000x reference)
//
#include <hip/hip_runtime.h>

namespace {

typedef float v2f __attribute__((ext_vector_type(2)));

constexpr int NTAGS = 64;
constexpr int START_T = 62;
constexpr int STOP_T = 63;
constexpr int Bc = 512;
constexpr int Lc = 512;

__device__ __forceinline__ float wave_max(float v) {
#pragma unroll
  for (int off = 32; off >= 1; off >>= 1)
    v = fmaxf(v, __shfl_xor(v, off, 64));
  return v;
}

__device__ __forceinline__ float wave_sum(float v) {
#pragma unroll
  for (int off = 32; off >= 1; off >>= 1)
    v += __shfl_xor(v, off, 64);
  return v;
}

// One wave handles TWO batches (bA = blockIdx.x, bB = bA + 256), phase-
// shifted by half a step so each batch's LDS write->read round trip hides
// under the other batch's 32 pk_fma. lane = tag row i (full wave per batch).
// Exp-domain state per batch: v_i = exp(alpha_i - Msum*ln2); per-step
// power-of-2 rescale from v_0's exponent (exact integer Msum bookkeeping).
// E = exp(trans) lives in 32 v2f registers, shared by both chains.
__global__ __launch_bounds__(64, 1) void crf_scan(
    const float* __restrict__ inputs,   // [B, L, 64]
    const int* __restrict__ tags,       // [B, L]
    const int* __restrict__ mask,       // [B, L]
    const float* __restrict__ trans,    // [64, 64]
    float* __restrict__ partial) {      // [B]
  __shared__ float4 bufA[16];
  __shared__ float4 bufB[16];
  float* bA1 = reinterpret_cast<float*>(bufA);
  float* bB1 = reinterpret_cast<float*>(bufB);

  const int lane = threadIdx.x;
  const int bA = blockIdx.x;
  const int bB = blockIdx.x + 256;

#define FOR16(X) X(0) X(1) X(2) X(3) X(4) X(5) X(6) X(7) \
                 X(8) X(9) X(10) X(11) X(12) X(13) X(14) X(15)

  // --- E = exp(trans[lane][:]) in registers, shared by both batches ---
#define DECL_E(q) v2f Ea##q, Eb##q;
  FOR16(DECL_E)
  {
    const float4* row = reinterpret_cast<const float4*>(trans + lane * NTAGS);
#define LOAD_E(q)                                     \
    {                                                 \
      float4 t = row[q];                              \
      Ea##q = (v2f){__expf(t.x), __expf(t.y)};        \
      Eb##q = (v2f){__expf(t.z), __expf(t.w)};        \
    }
    FOR16(LOAD_E)
  }

  const float* embA = inputs + (size_t)bA * Lc * NTAGS;
  const float* embB = inputs + (size_t)bB * Lc * NTAGS;
  const float* emA = embA + lane;
  const float* emB = embB + lane;
  const int* mAp = mask + bA * Lc;
  const int* mBp = mask + bB * Lc;

  int MsA = 0, MsB = 0;
  bA1[lane] = (lane == START_T) ? 1.0f : 0.0f;
  bB1[lane] = (lane == START_T) ? 1.0f : 0.0f;
  __builtin_amdgcn_wave_barrier();

  float4 uA[16], uB[16];
#define ULOAD(U, BUF)                                  \
  { _Pragma("unroll") for (int q_ = 0; q_ < 16; ++q_) U[q_] = BUF[q_]; }

#define MF(U, q, A, B)                                \
    {                                                 \
      float4 uu = U[q];                               \
      A += Ea##q * (v2f){uu.x, uu.y};                 \
      B += Eb##q * (v2f){uu.z, uu.w};                 \
    }
#define MSUM(U, q, A, B)                              \
    {                                                 \
      float4 uu = U[q];                               \
      A += (v2f){uu.x, uu.y};                         \
      B += (v2f){uu.z, uu.w};                         \
    }

#define COMPUTE(U, W, MROW, MIDX, MS, SOUT)                                 \
    float SOUT;                                                             \
    {                                                                       \
      const int sb_ =                                                       \
          __builtin_amdgcn_readfirstlane(__float_as_int(U[0].x));           \
      const unsigned e0_ = ((unsigned)sb_ >> 23) & 0xffu;                   \
      const int d_ = (e0_ == 0u) ? 0 : (int)e0_ - 127;                      \
      MS += d_;                                                             \
      const float rs_ = __uint_as_float((unsigned)(127 - d_) << 23);        \
      const int mv_ = __builtin_amdgcn_readlane(MROW, (MIDX));              \
      if (mv_) {                                                            \
        v2f a0 = {0.f, 0.f}, a1 = {0.f, 0.f};                               \
        v2f a2 = {0.f, 0.f}, a3 = {0.f, 0.f};                               \
        MF(U, 0, a0, a1) MF(U, 1, a2, a3) MF(U, 2, a0, a1)                  \
        MF(U, 3, a2, a3) MF(U, 4, a0, a1) MF(U, 5, a2, a3)                  \
        MF(U, 6, a0, a1) MF(U, 7, a2, a3) MF(U, 8, a0, a1)                  \
        MF(U, 9, a2, a3) MF(U, 10, a0, a1) MF(U, 11, a2, a3)                \
        MF(U, 12, a0, a1) MF(U, 13, a2, a3) MF(U, 14, a0, a1)               \
        MF(U, 15, a2, a3)                                                   \
        v2f t_ = (a0 + a1) + (a2 + a3);                                     \
        SOUT = (t_.x + t_.y) * ((W) * rs_);                                 \
      } else {                                                              \
        v2f a0 = {0.f, 0.f}, a1 = {0.f, 0.f};                               \
        MSUM(U, 0, a0, a1) MSUM(U, 1, a0, a1) MSUM(U, 2, a0, a1)            \
        MSUM(U, 3, a0, a1) MSUM(U, 4, a0, a1) MSUM(U, 5, a0, a1)            \
        MSUM(U, 6, a0, a1) MSUM(U, 7, a0, a1) MSUM(U, 8, a0, a1)            \
        MSUM(U, 9, a0, a1) MSUM(U, 10, a0, a1) MSUM(U, 11, a0, a1)          \
        MSUM(U, 12, a0, a1) MSUM(U, 13, a0, a1) MSUM(U, 14, a0, a1)         \
        MSUM(U, 15, a0, a1)                                                 \
        v2f t_ = a0 + a1;                                                   \
        SOUT = (t_.x + t_.y) * rs_;                                         \
      }                                                                     \
    }

  // Phase-shifted iteration: A's write->reload latency hides under B's
  // compute; B's hides under next iteration's A compute.
#define ITER(WA_, WB_, MIDX)                           \
  {                                                    \
    COMPUTE(uA, WA_, mrA, MIDX, MsA, sA_)              \
    __builtin_amdgcn_wave_barrier();                   \
    bA1[lane] = sA_;                                   \
    __builtin_amdgcn_wave_barrier();                   \
    ULOAD(uA, bufA)                                    \
    COMPUTE(uB, WB_, mrB, MIDX, MsB, sB_)              \
    __builtin_amdgcn_wave_barrier();                   \
    bB1[lane] = sB_;                                   \
    __builtin_amdgcn_wave_barrier();                   \
    ULOAD(uB, bufB)                                    \
  }

  // w = exp(emit) prefetch, two rotating banks of 4 steps per batch.
#define PRE(Wb, EM, ST)                                                \
  {                                                                    \
    int s_ = (ST); s_ = s_ > (Lc - 4) ? (Lc - 4) : s_;                 \
    _Pragma("unroll") for (int q_ = 0; q_ < 4; ++q_)                   \
        Wb[q_] = __expf(EM[(size_t)(s_ + q_) * NTAGS]);                \
  }

  float wA0[4], wA1v[4], wB0[4], wB1v[4];
  PRE(wA0, emA, 0)
  PRE(wB0, emB, 0)
  int mrA = mAp[lane];
  int mrB = mBp[lane];

  ULOAD(uA, bufA)
  ULOAD(uB, bufB)

  for (int chunk = 0; chunk < 8; ++chunk) {
    const int cbase = chunk * 64;
    const int nb = (chunk < 7 ? cbase + 64 : cbase) + lane;
    int mrA_nxt = mAp[nb];
    int mrB_nxt = mBp[nb];
    for (int gp = 0; gp < 8; ++gp) {
      const int base = cbase + gp * 8;
      const int mb = gp * 8;
      PRE(wA1v, emA, base + 4)
      PRE(wB1v, emB, base + 4)
      ITER(wA0[0], wB0[0], mb + 0)
      ITER(wA0[1], wB0[1], mb + 1)
      ITER(wA0[2], wB0[2], mb + 2)
      ITER(wA0[3], wB0[3], mb + 3)
      PRE(wA0, emA, base + 8)
      PRE(wB0, emB, base + 8)
      ITER(wA1v[0], wB1v[0], mb + 4)
      ITER(wA1v[1], wB1v[1], mb + 5)
      ITER(wA1v[2], wB1v[2], mb + 6)
      ITER(wA1v[3], wB1v[3], mb + 7)
    }
    mrA = mrA_nxt;
    mrB = mrB_nxt;
  }

  // ---- epilogue (exact; same as verified rounds), done per batch ----
#define EPILOGUE(BUF1, MS, EMB, BIDX, MP)                              \
  {                                                                    \
    const float mf_ = (float)(MS);                                     \
    const float C_ = fmaf(mf_, -2.1219444e-4f, mf_ * 0.693359375f);    \
    float alphav = __logf(BUF1[lane]) + C_;                            \
    float term = alphav + trans[STOP_T * NTAGS + lane];                \
    float mx = wave_max(term);                                         \
    float sden = wave_sum(__expf(term - mx));                          \
    float logden = mx + __logf(sden);                                  \
    const int* tb_ = tags + (BIDX) * Lc;                               \
    float sc = 0.0f;                                                   \
    for (int l = lane; l < Lc; l += 64) {                              \
      int tl = tb_[l];                                                 \
      float mfl = (float)MP[l];                                        \
      if (l < Lc - 1) {                                                \
        int tn = tb_[l + 1];                                           \
        float mfn = (float)MP[l + 1];                                  \
        sc += trans[tn * NTAGS + tl] * mfn +                           \
              (EMB)[(size_t)l * NTAGS + tl] * mfl;                     \
      } else {                                                         \
        sc += trans[STOP_T * NTAGS + tl] +                             \
              (EMB)[(size_t)l * NTAGS + tl] * mfl;                     \
      }                                                                \
    }                                                                  \
    if (lane == 0) sc += trans[tb_[0] * NTAGS + START_T];              \
    float score = wave_sum(sc);                                        \
    if (lane == 0) partial[BIDX] = score - logden;                     \
  }

  EPILOGUE(bA1, MsA, embA, bA, mAp)
  EPILOGUE(bB1, MsB, embB, bB, mBp)
}

__global__ void crf_reduce(const float* __restrict__ partial,
                           float* __restrict__ out) {
  const int lane = threadIdx.x;
  float s = 0.0f;
  for (int i = lane; i < Bc; i += 64) s += partial[i];
  s = wave_sum(s);
  if (lane == 0) out[0] = s;
}

}  // namespace

extern "C" void kernel_launch(void* const* d_in, const int* in_sizes, int n_in,
                              void* d_out, int out_size, void* d_ws,
                              size_t ws_size, hipStream_t stream) {
  const float* inputs = (const float*)d_in[0];
  const int* tags = (const int*)d_in[1];
  const int* mask = (const int*)d_in[2];
  const float* trans = (const float*)d_in[3];
  float* out = (float*)d_out;
  float* partial = (float*)d_ws;  // B floats of scratch

  crf_scan<<<Bc / 2, 64, 0, stream>>>(inputs, tags, mask, trans, partial);
  crf_reduce<<<1, 64, 0, stream>>>(partial, out);
}